// Round 5
// baseline (84.509 us; speedup 1.0000x reference)
//
#include <hip/hip_runtime.h>
#include <hip/hip_bf16.h>

typedef short bf16x8 __attribute__((ext_vector_type(8)));
typedef float f32x4  __attribute__((ext_vector_type(4)));

#define Bn 4
#define Cn 64
#define Hn 128
#define Wn 128
#define On 64
#define HWn 16384

// ws layout (bytes):
//   xt     [B][H][W][C] bf16   @ 0
//   off    [B][36][H][W] f32   @ XT_BYTES
//   pk_def [18][4][64][8] bf16 @ XT+OFF        B-frags, main conv
//   pk_off [18][3][64][8] bf16 @ XT+OFF+PKDEF  B-frags, offset conv
#define XT_BYTES    (Bn*HWn*Cn*2)
#define OFF_BYTES   (Bn*36*HWn*4)
#define PKDEF_BYTES (18*4*64*8*2)

static __device__ __forceinline__ unsigned pk_bf16(float lo, float hi) {
  union { __hip_bfloat162 h; unsigned u; } cv;
  cv.h = __float22bfloat162_rn(make_float2(lo, hi));
  return cv.u;
}
static __device__ __forceinline__ float blo(unsigned u) { return __uint_as_float(u << 16); }
static __device__ __forceinline__ float bhi(unsigned u) { return __uint_as_float(u & 0xffff0000u); }

// ---- x: NCHW f32 -> NHWC bf16, LDS-tiled transpose (64 pix x 64 ch per block)
__global__ __launch_bounds__(256) void transpose_cast(const float* __restrict__ x,
                                                      ushort* __restrict__ xt) {
  __shared__ float tile[64][65];
  const int t = threadIdx.x;
  const int blk = blockIdx.x;            // 1024 = B * (HW/64)
  const int b = blk >> 8;
  const int pix0 = (blk & 255) * 64;
  const float* xb = x + (b * Cn) * HWn + pix0;
#pragma unroll
  for (int q = 0; q < 16; ++q) {
    int idx = q * 256 + t;
    int c = idx >> 6, p = idx & 63;
    tile[c][p] = xb[c * HWn + p];
  }
  __syncthreads();
  const int p = t >> 2, cg = t & 3;
  unsigned u[8];
#pragma unroll
  for (int j = 0; j < 8; ++j)
    u[j] = pk_bf16(tile[cg * 16 + 2 * j][p], tile[cg * 16 + 2 * j + 1][p]);
  ushort* dst = xt + ((b * HWn + pix0 + p) * 64 + cg * 16);
  uint4 v0 = {u[0], u[1], u[2], u[3]}, v1 = {u[4], u[5], u[6], u[7]};
  *(uint4*)dst = v0;
  *(uint4*)(dst + 8) = v1;
}

// ---- pack weights as MFMA B-fragments (K-slice = 32 channels)
__global__ __launch_bounds__(256) void prep_pack(const float* __restrict__ w_off,
                                                 const float* __restrict__ w_def,
                                                 ushort* __restrict__ pk_def,
                                                 ushort* __restrict__ pk_off) {
  const int t = blockIdx.x * 256 + threadIdx.x;
  if (t < 4608) {                        // 18*4*64
    int lane = t & 63, oc = (t >> 6) & 3, s = t >> 8;
    int g = s / 9, k = s % 9;
    int o = oc * 16 + (lane & 15);
    int cb = g * 32 + (lane >> 4) * 8;
    unsigned u[4];
#pragma unroll
    for (int j = 0; j < 4; ++j)
      u[j] = pk_bf16(w_def[(o * Cn + cb + 2 * j) * 9 + k],
                     w_def[(o * Cn + cb + 2 * j + 1) * 9 + k]);
    uint4 v = {u[0], u[1], u[2], u[3]};
    *(uint4*)(pk_def + t * 8) = v;
  } else if (t < 8064) {                 // + 18*3*64
    int t2 = t - 4608;
    int lane = t2 & 63, r = t2 >> 6;     // r = s*3 + oc
    int oc = r % 3, s = r / 3;
    int k = s >> 1, chalf = s & 1;
    int o = oc * 16 + (lane & 15);
    int cb = chalf * 32 + (lane >> 4) * 8;
    unsigned u[4];
#pragma unroll
    for (int j = 0; j < 4; ++j) {
      float lo = (o < 36) ? w_off[(o * Cn + cb + 2 * j) * 9 + k] : 0.f;
      float hi = (o < 36) ? w_off[(o * Cn + cb + 2 * j + 1) * 9 + k] : 0.f;
      u[j] = pk_bf16(lo, hi);
    }
    uint4 v = {u[0], u[1], u[2], u[3]};
    *(uint4*)(pk_off + (r * 64 + lane) * 8) = v;
  }
}

// ---- offset conv via MFMA, 2-way K-split (slices 0-8 vs 9-17) + LDS reduce.
// Block = 512 thr = 8 waves = 4 pixel-groups x 2 halves. Grid 1024, 8/SIMD.
__global__ __launch_bounds__(512, 8) void offs_conv_mfma(const ushort* __restrict__ xt,
                                                         const ushort* __restrict__ pk_off,
                                                         float* __restrict__ off) {
  __shared__ float red[4][3][64][4];     // 12 KB
  const int lane = threadIdx.x & 63;
  const int wid = threadIdx.x >> 6;
  const int pg = wid >> 1, ssel = wid & 1;
  int bid = blockIdx.x;
  bid = (bid & 7) * 128 + (bid >> 3);    // 1024 blocks, bijective XCD swizzle
  const int gp0 = bid * 64 + pg * 16;
  const int b = gp0 >> 14;
  const int pixin = gp0 & 16383;
  const int h = pixin >> 7;
  const int p = lane & 15, kq = lane >> 4;
  const int w_ = (pixin & 127) + p;

  f32x4 acc0 = {0,0,0,0}, acc1 = {0,0,0,0}, acc2 = {0,0,0,0};
  const bf16x8* pB = (const bf16x8*)pk_off;

  uint4 av[2];
#define OLOADA(j, dst) {                                                      \
    const int s_ = ssel * 9 + (j);                                            \
    const int k = s_ >> 1, chalf = s_ & 1;                                    \
    int y = h + k / 3 - 1, xx = w_ + k % 3 - 1;                               \
    bool valid = ((unsigned)y < 128u) && ((unsigned)xx < 128u);               \
    int yc = min(max(y, 0), 127), xc = min(max(xx, 0), 127);                  \
    uint4 t_ = *(const uint4*)(xt + (((b << 14) + (yc << 7) + xc) << 6)       \
                               + chalf * 32 + kq * 8);                        \
    if (!valid) { t_.x = 0; t_.y = 0; t_.z = 0; t_.w = 0; }                   \
    dst = t_; }

  OLOADA(0, av[0])
#pragma unroll
  for (int j = 0; j < 9; ++j) {
    if (j + 1 < 9) OLOADA(j + 1, av[(j + 1) & 1])
    union { uint4 u; bf16x8 v; } A; A.u = av[j & 1];
    const int s = ssel * 9 + j;
    acc0 = __builtin_amdgcn_mfma_f32_16x16x32_bf16(A.v, pB[(s*3 + 0)*64 + lane], acc0, 0,0,0);
    acc1 = __builtin_amdgcn_mfma_f32_16x16x32_bf16(A.v, pB[(s*3 + 1)*64 + lane], acc1, 0,0,0);
    acc2 = __builtin_amdgcn_mfma_f32_16x16x32_bf16(A.v, pB[(s*3 + 2)*64 + lane], acc2, 0,0,0);
  }
#undef OLOADA

  if (ssel == 1) {
    *(f32x4*)red[pg][0][lane] = acc0;
    *(f32x4*)red[pg][1][lane] = acc1;
    *(f32x4*)red[pg][2][lane] = acc2;
  }
  __syncthreads();
  if (ssel == 0) {
    acc0 += *(const f32x4*)red[pg][0][lane];
    acc1 += *(const f32x4*)red[pg][1][lane];
    acc2 += *(const f32x4*)red[pg][2][lane];
    float* ob = off + pixin + kq * 4;
    const int colb = lane & 15;
#pragma unroll
    for (int r = 0; r < 4; ++r) {
      ob[((b*36 +      colb) << 14) + r] = acc0[r];
      ob[((b*36 + 16 + colb) << 14) + r] = acc1[r];
      if (colb < 4) ob[((b*36 + 32 + colb) << 14) + r] = acc2[r];
    }
  }
}

// ---- main deformable conv via MFMA, 2-way K-split over deformable group g.
// Block = 512 thr = 8 waves = 4 pixel-groups x 2 groups. Grid 1024, 8/SIMD.
__global__ __launch_bounds__(512, 8) void deform_main_mfma(const ushort* __restrict__ xt,
                                                           const ushort* __restrict__ pk_def,
                                                           const float* __restrict__ off,
                                                           float* __restrict__ out) {
  __shared__ float red[4][4][64][4];     // 16 KB
  const int lane = threadIdx.x & 63;
  const int wid = threadIdx.x >> 6;
  const int pg = wid >> 1, gsel = wid & 1;
  int bid = blockIdx.x;
  bid = (bid & 7) * 128 + (bid >> 3);    // XCD swizzle, 1024 blocks
  const int gp0 = bid * 64 + pg * 16;
  const int b = gp0 >> 14;
  const int pixin = gp0 & 16383;
  const int h = pixin >> 7;
  const int p = lane & 15, kq = lane >> 4;
  const int w_ = (pixin & 127) + p;
  const int imgb = b << 14;
  const int cb = gsel * 32 + kq * 8;

  // this wave's group: 18 offset channels, coalesced L2-hot loads
  const float* offb = off + ((b * 36 + gsel * 18) << 14) + pixin + p;
  float offv[18];
#pragma unroll
  for (int j = 0; j < 18; ++j) offv[j] = offb[j << 14];

  f32x4 acc0={0,0,0,0}, acc1={0,0,0,0}, acc2={0,0,0,0}, acc3={0,0,0,0};
  const bf16x8* pB = (const bf16x8*)pk_def;

  struct Stage { float w00, w01, w10, w11; uint4 c00, c01, c10, c11; };
  Stage st[2];

#define DPREP(j, S) {                                                          \
    const int k = (j);                                                         \
    float py = offv[2*(j)]   + (float)(h  + k / 3 - 1);                        \
    float px = offv[2*(j)+1] + (float)(w_ + k % 3 - 1);                        \
    float fy = floorf(py), fx = floorf(px);                                    \
    int y0 = (int)fy, x0 = (int)fx;                                            \
    float dy = py - fy, dx = px - fx;                                          \
    bool vy0 = (y0 >= 0) && (y0 < Hn);                                         \
    bool vy1 = (y0 >= -1) && (y0 < Hn - 1);                                    \
    bool vx0 = (x0 >= 0) && (x0 < Wn);                                         \
    bool vx1 = (x0 >= -1) && (x0 < Wn - 1);                                    \
    float omdy = 1.f - dy, omdx = 1.f - dx;                                    \
    S.w00 = (vy0 && vx0) ? omdy * omdx : 0.f;                                  \
    S.w01 = (vy0 && vx1) ? omdy * dx   : 0.f;                                  \
    S.w10 = (vy1 && vx0) ? dy * omdx   : 0.f;                                  \
    S.w11 = (vy1 && vx1) ? dy * dx     : 0.f;                                  \
    int iy0 = min(max(y0, 0), Hn - 1), iy1 = min(max(y0 + 1, 0), Hn - 1);      \
    int ix0 = min(max(x0, 0), Wn - 1), ix1 = min(max(x0 + 1, 0), Wn - 1);      \
    int rb0 = imgb + (iy0 << 7), rb1 = imgb + (iy1 << 7);                      \
    S.c00 = *(const uint4*)(xt + ((rb0 + ix0) << 6) + cb);                     \
    S.c01 = *(const uint4*)(xt + ((rb0 + ix1) << 6) + cb);                     \
    S.c10 = *(const uint4*)(xt + ((rb1 + ix0) << 6) + cb);                     \
    S.c11 = *(const uint4*)(xt + ((rb1 + ix1) << 6) + cb); }

  DPREP(0, st[0])
#pragma unroll
  for (int j = 0; j < 9; ++j) {
    if (j + 1 < 9) DPREP(j + 1, st[(j + 1) & 1])
    Stage& S = st[j & 1];
    const int s = gsel * 9 + j;
    unsigned au[4];
#define BILC(comp, idx)                                                               \
    { float l = S.w00 * blo(S.c00.comp); l = fmaf(S.w01, blo(S.c01.comp), l);         \
      l = fmaf(S.w10, blo(S.c10.comp), l); l = fmaf(S.w11, blo(S.c11.comp), l);       \
      float hh = S.w00 * bhi(S.c00.comp); hh = fmaf(S.w01, bhi(S.c01.comp), hh);      \
      hh = fmaf(S.w10, bhi(S.c10.comp), hh); hh = fmaf(S.w11, bhi(S.c11.comp), hh);   \
      au[idx] = pk_bf16(l, hh); }
    BILC(x, 0) BILC(y, 1) BILC(z, 2) BILC(w, 3)
#undef BILC
    union { uint4 u; bf16x8 v; } A;
    A.u.x = au[0]; A.u.y = au[1]; A.u.z = au[2]; A.u.w = au[3];

    acc0 = __builtin_amdgcn_mfma_f32_16x16x32_bf16(A.v, pB[(s*4 + 0)*64 + lane], acc0, 0,0,0);
    acc1 = __builtin_amdgcn_mfma_f32_16x16x32_bf16(A.v, pB[(s*4 + 1)*64 + lane], acc1, 0,0,0);
    acc2 = __builtin_amdgcn_mfma_f32_16x16x32_bf16(A.v, pB[(s*4 + 2)*64 + lane], acc2, 0,0,0);
    acc3 = __builtin_amdgcn_mfma_f32_16x16x32_bf16(A.v, pB[(s*4 + 3)*64 + lane], acc3, 0,0,0);
  }
#undef DPREP

  if (gsel == 1) {
    *(f32x4*)red[pg][0][lane] = acc0;
    *(f32x4*)red[pg][1][lane] = acc1;
    *(f32x4*)red[pg][2][lane] = acc2;
    *(f32x4*)red[pg][3][lane] = acc3;
  }
  __syncthreads();
  if (gsel == 0) {
    acc0 += *(const f32x4*)red[pg][0][lane];
    acc1 += *(const f32x4*)red[pg][1][lane];
    acc2 += *(const f32x4*)red[pg][2][lane];
    acc3 += *(const f32x4*)red[pg][3][lane];
    float* ob = out + pixin + kq * 4;
    const int colb = lane & 15;
#pragma unroll
    for (int r = 0; r < 4; ++r) {
      ob[((b*64 +      colb) << 14) + r] = acc0[r];
      ob[((b*64 + 16 + colb) << 14) + r] = acc1[r];
      ob[((b*64 + 32 + colb) << 14) + r] = acc2[r];
      ob[((b*64 + 48 + colb) << 14) + r] = acc3[r];
    }
  }
}

extern "C" void kernel_launch(void* const* d_in, const int* in_sizes, int n_in,
                              void* d_out, int out_size, void* d_ws, size_t ws_size,
                              hipStream_t stream) {
  const float* x     = (const float*)d_in[0];
  const float* w_off = (const float*)d_in[1];
  const float* w_def = (const float*)d_in[2];
  float* out = (float*)d_out;

  char* ws = (char*)d_ws;
  ushort* xt     = (ushort*)ws;
  float*  off    = (float*)(ws + XT_BYTES);
  ushort* pk_def = (ushort*)(ws + XT_BYTES + OFF_BYTES);
  ushort* pk_off = (ushort*)(ws + XT_BYTES + OFF_BYTES + PKDEF_BYTES);

  transpose_cast<<<1024, 256, 0, stream>>>(x, xt);
  prep_pack<<<32, 256, 0, stream>>>(w_off, w_def, pk_def, pk_off);
  offs_conv_mfma<<<1024, 512, 0, stream>>>(xt, pk_off, off);
  deform_main_mfma<<<1024, 512, 0, stream>>>(xt, pk_def, off, out);
}

// Round 6
// 82.367 us; speedup vs baseline: 1.0260x; 1.0260x over previous
//
#include <hip/hip_runtime.h>
#include <hip/hip_bf16.h>

typedef short bf16x8 __attribute__((ext_vector_type(8)));
typedef float f32x4  __attribute__((ext_vector_type(4)));

#define Bn 4
#define Cn 64
#define Hn 128
#define Wn 128
#define On 64
#define HWn 16384

// ws layout (bytes):
//   xt     [B][H][seg0..7][W][8ch] bf16 @ 0        (8 MB)  seg = channel octet
//   off    [B][36][H][W] f32   @ XT_BYTES
//   pk_def [18][4][64][8] bf16 @ XT+OFF
//   pk_off [18][3][64][8] bf16 @ XT+OFF+PKDEF
#define XT_BYTES    (Bn*HWn*Cn*2)
#define OFF_BYTES   (Bn*36*HWn*4)
#define PKDEF_BYTES (18*4*64*8*2)

static __device__ __forceinline__ unsigned pk_bf16(float lo, float hi) {
  union { __hip_bfloat162 h; unsigned u; } cv;
  cv.h = __float22bfloat162_rn(make_float2(lo, hi));
  return cv.u;
}
static __device__ __forceinline__ float blo(unsigned u) { return __uint_as_float(u << 16); }
static __device__ __forceinline__ float bhi(unsigned u) { return __uint_as_float(u & 0xffff0000u); }

// ---- x: NCHW f32 -> [b][y][seg][x][8] bf16. Block = 64 px (one row segment) x 64 ch.
__global__ __launch_bounds__(256) void transpose_cast(const float* __restrict__ x,
                                                      ushort* __restrict__ xt) {
  __shared__ float tile[64][65];
  const int t = threadIdx.x;
  const int blk = blockIdx.x;            // 1024 = B * 256
  const int b = blk >> 8;
  const int pix0 = (blk & 255) * 64;
  const int y = pix0 >> 7, x0 = pix0 & 127;
  const float* xb = x + (b * Cn) * HWn + pix0;
#pragma unroll
  for (int q = 0; q < 16; ++q) {
    int idx = q * 256 + t;
    int c = idx >> 6, p = idx & 63;
    tile[c][p] = xb[c * HWn + p];
  }
  __syncthreads();
  const int p = t & 63, cg = t >> 6;     // lanes = consecutive pixels -> coalesced stores
#pragma unroll
  for (int half = 0; half < 2; ++half) {
    const int seg = cg * 2 + half;
    unsigned u[4];
#pragma unroll
    for (int j = 0; j < 4; ++j)
      u[j] = pk_bf16(tile[seg * 8 + 2 * j][p], tile[seg * 8 + 2 * j + 1][p]);
    uint4 v = {u[0], u[1], u[2], u[3]};
    *(uint4*)(xt + (((((b << 7) + y) << 3) + seg) * 128 + x0 + p) * 8) = v;
  }
}

// ---- pack weights as MFMA B-fragments (K-slice = 32 channels) — layout-independent
__global__ __launch_bounds__(256) void prep_pack(const float* __restrict__ w_off,
                                                 const float* __restrict__ w_def,
                                                 ushort* __restrict__ pk_def,
                                                 ushort* __restrict__ pk_off) {
  const int t = blockIdx.x * 256 + threadIdx.x;
  if (t < 4608) {                        // 18*4*64
    int lane = t & 63, oc = (t >> 6) & 3, s = t >> 8;
    int g = s / 9, k = s % 9;
    int o = oc * 16 + (lane & 15);
    int cb = g * 32 + (lane >> 4) * 8;
    unsigned u[4];
#pragma unroll
    for (int j = 0; j < 4; ++j)
      u[j] = pk_bf16(w_def[(o * Cn + cb + 2 * j) * 9 + k],
                     w_def[(o * Cn + cb + 2 * j + 1) * 9 + k]);
    uint4 v = {u[0], u[1], u[2], u[3]};
    *(uint4*)(pk_def + t * 8) = v;
  } else if (t < 8064) {                 // + 18*3*64
    int t2 = t - 4608;
    int lane = t2 & 63, r = t2 >> 6;     // r = s*3 + oc
    int oc = r % 3, s = r / 3;
    int k = s >> 1, chalf = s & 1;
    int o = oc * 16 + (lane & 15);
    int cb = chalf * 32 + (lane >> 4) * 8;
    unsigned u[4];
#pragma unroll
    for (int j = 0; j < 4; ++j) {
      float lo = (o < 36) ? w_off[(o * Cn + cb + 2 * j) * 9 + k] : 0.f;
      float hi = (o < 36) ? w_off[(o * Cn + cb + 2 * j + 1) * 9 + k] : 0.f;
      u[j] = pk_bf16(lo, hi);
    }
    uint4 v = {u[0], u[1], u[2], u[3]};
    *(uint4*)(pk_off + (r * 64 + lane) * 8) = v;
  }
}

// ---- offset conv via MFMA, 2-way K-split + LDS reduce. Grid 1024 x 512thr, 8/SIMD.
__global__ __launch_bounds__(512, 8) void offs_conv_mfma(const ushort* __restrict__ xt,
                                                         const ushort* __restrict__ pk_off,
                                                         float* __restrict__ off) {
  __shared__ float red[4][3][64][4];     // 12 KB
  const int lane = threadIdx.x & 63;
  const int wid = threadIdx.x >> 6;
  const int pg = wid >> 1, ssel = wid & 1;
  int bid = blockIdx.x;
  bid = (bid & 7) * 128 + (bid >> 3);    // bijective XCD swizzle (1024 % 8 == 0)
  const int gp0 = bid * 64 + pg * 16;
  const int b = gp0 >> 14;
  const int pixin = gp0 & 16383;
  const int h = pixin >> 7;
  const int p = lane & 15, kq = lane >> 4;
  const int w_ = (pixin & 127) + p;

  f32x4 acc0 = {0,0,0,0}, acc1 = {0,0,0,0}, acc2 = {0,0,0,0};
  const bf16x8* pB = (const bf16x8*)pk_off;

  uint4 av[2];
#define OLOADA(j, dst) {                                                      \
    const int s_ = ssel * 9 + (j);                                            \
    const int k = s_ >> 1, chalf = s_ & 1;                                    \
    int y = h + k / 3 - 1, xx = w_ + k % 3 - 1;                               \
    bool valid = ((unsigned)y < 128u) && ((unsigned)xx < 128u);               \
    int yc = min(max(y, 0), 127), xc = min(max(xx, 0), 127);                  \
    const int seg = chalf * 4 + kq;                                           \
    uint4 t_ = *(const uint4*)(xt +                                           \
        (((((b << 7) + yc) << 3) + seg) * 128 + xc) * 8);                     \
    if (!valid) { t_.x = 0; t_.y = 0; t_.z = 0; t_.w = 0; }                   \
    dst = t_; }

  OLOADA(0, av[0])
#pragma unroll
  for (int j = 0; j < 9; ++j) {
    if (j + 1 < 9) OLOADA(j + 1, av[(j + 1) & 1])
    union { uint4 u; bf16x8 v; } A; A.u = av[j & 1];
    const int s = ssel * 9 + j;
    acc0 = __builtin_amdgcn_mfma_f32_16x16x32_bf16(A.v, pB[(s*3 + 0)*64 + lane], acc0, 0,0,0);
    acc1 = __builtin_amdgcn_mfma_f32_16x16x32_bf16(A.v, pB[(s*3 + 1)*64 + lane], acc1, 0,0,0);
    acc2 = __builtin_amdgcn_mfma_f32_16x16x32_bf16(A.v, pB[(s*3 + 2)*64 + lane], acc2, 0,0,0);
  }
#undef OLOADA

  if (ssel == 1) {
    *(f32x4*)red[pg][0][lane] = acc0;
    *(f32x4*)red[pg][1][lane] = acc1;
    *(f32x4*)red[pg][2][lane] = acc2;
  }
  __syncthreads();
  if (ssel == 0) {
    acc0 += *(const f32x4*)red[pg][0][lane];
    acc1 += *(const f32x4*)red[pg][1][lane];
    acc2 += *(const f32x4*)red[pg][2][lane];
    float* ob = off + pixin + kq * 4;
    const int colb = lane & 15;
#pragma unroll
    for (int r = 0; r < 4; ++r) {
      ob[((b*36 +      colb) << 14) + r] = acc0[r];
      ob[((b*36 + 16 + colb) << 14) + r] = acc1[r];
      if (colb < 4) ob[((b*36 + 32 + colb) << 14) + r] = acc2[r];
    }
  }
}

// ---- main deformable conv via MFMA, 2-way split over group g. Grid 1024 x 512thr.
__global__ __launch_bounds__(512, 8) void deform_main_mfma(const ushort* __restrict__ xt,
                                                           const ushort* __restrict__ pk_def,
                                                           const float* __restrict__ off,
                                                           float* __restrict__ out) {
  __shared__ float red[4][4][64][4];     // 16 KB
  const int lane = threadIdx.x & 63;
  const int wid = threadIdx.x >> 6;
  const int pg = wid >> 1, gsel = wid & 1;
  int bid = blockIdx.x;
  bid = (bid & 7) * 128 + (bid >> 3);    // XCD swizzle
  const int gp0 = bid * 64 + pg * 16;
  const int b = gp0 >> 14;
  const int pixin = gp0 & 16383;
  const int h = pixin >> 7;
  const int p = lane & 15, kq = lane >> 4;
  const int w_ = (pixin & 127) + p;
  const int su = gsel * 4 + kq;          // channel octet this lane gathers

  const float* offb = off + ((b * 36 + gsel * 18) << 14) + pixin + p;
  float offv[18];
#pragma unroll
  for (int j = 0; j < 18; ++j) offv[j] = offb[j << 14];

  f32x4 acc0={0,0,0,0}, acc1={0,0,0,0}, acc2={0,0,0,0}, acc3={0,0,0,0};
  const bf16x8* pB = (const bf16x8*)pk_def;

  struct Stage { float w00, w01, w10, w11; uint4 c00, c01, c10, c11; };
  Stage st[2];

#define DPREP(j, S) {                                                          \
    const int k = (j);                                                         \
    float py = offv[2*(j)]   + (float)(h  + k / 3 - 1);                        \
    float px = offv[2*(j)+1] + (float)(w_ + k % 3 - 1);                        \
    float fy = floorf(py), fx = floorf(px);                                    \
    int y0 = (int)fy, x0 = (int)fx;                                            \
    float dy = py - fy, dx = px - fx;                                          \
    bool vy0 = (y0 >= 0) && (y0 < Hn);                                         \
    bool vy1 = (y0 >= -1) && (y0 < Hn - 1);                                    \
    bool vx0 = (x0 >= 0) && (x0 < Wn);                                         \
    bool vx1 = (x0 >= -1) && (x0 < Wn - 1);                                    \
    float omdy = 1.f - dy, omdx = 1.f - dx;                                    \
    S.w00 = (vy0 && vx0) ? omdy * omdx : 0.f;                                  \
    S.w01 = (vy0 && vx1) ? omdy * dx   : 0.f;                                  \
    S.w10 = (vy1 && vx0) ? dy * omdx   : 0.f;                                  \
    S.w11 = (vy1 && vx1) ? dy * dx     : 0.f;                                  \
    int iy0 = min(max(y0, 0), Hn - 1), iy1 = min(max(y0 + 1, 0), Hn - 1);      \
    int ix0 = min(max(x0, 0), Wn - 1), ix1 = min(max(x0 + 1, 0), Wn - 1);      \
    const int r0 = ((((b << 7) + iy0) << 3) + su) * 128;                       \
    const int r1 = ((((b << 7) + iy1) << 3) + su) * 128;                       \
    S.c00 = *(const uint4*)(xt + (r0 + ix0) * 8);                              \
    S.c01 = *(const uint4*)(xt + (r0 + ix1) * 8);                              \
    S.c10 = *(const uint4*)(xt + (r1 + ix0) * 8);                              \
    S.c11 = *(const uint4*)(xt + (r1 + ix1) * 8); }

  DPREP(0, st[0])
#pragma unroll
  for (int j = 0; j < 9; ++j) {
    if (j + 1 < 9) DPREP(j + 1, st[(j + 1) & 1])
    Stage& S = st[j & 1];
    const int s = gsel * 9 + j;
    unsigned au[4];
#define BILC(comp, idx)                                                               \
    { float l = S.w00 * blo(S.c00.comp); l = fmaf(S.w01, blo(S.c01.comp), l);         \
      l = fmaf(S.w10, blo(S.c10.comp), l); l = fmaf(S.w11, blo(S.c11.comp), l);       \
      float hh = S.w00 * bhi(S.c00.comp); hh = fmaf(S.w01, bhi(S.c01.comp), hh);      \
      hh = fmaf(S.w10, bhi(S.c10.comp), hh); hh = fmaf(S.w11, bhi(S.c11.comp), hh);   \
      au[idx] = pk_bf16(l, hh); }
    BILC(x, 0) BILC(y, 1) BILC(z, 2) BILC(w, 3)
#undef BILC
    union { uint4 u; bf16x8 v; } A;
    A.u.x = au[0]; A.u.y = au[1]; A.u.z = au[2]; A.u.w = au[3];

    acc0 = __builtin_amdgcn_mfma_f32_16x16x32_bf16(A.v, pB[(s*4 + 0)*64 + lane], acc0, 0,0,0);
    acc1 = __builtin_amdgcn_mfma_f32_16x16x32_bf16(A.v, pB[(s*4 + 1)*64 + lane], acc1, 0,0,0);
    acc2 = __builtin_amdgcn_mfma_f32_16x16x32_bf16(A.v, pB[(s*4 + 2)*64 + lane], acc2, 0,0,0);
    acc3 = __builtin_amdgcn_mfma_f32_16x16x32_bf16(A.v, pB[(s*4 + 3)*64 + lane], acc3, 0,0,0);
  }
#undef DPREP

  if (gsel == 1) {
    *(f32x4*)red[pg][0][lane] = acc0;
    *(f32x4*)red[pg][1][lane] = acc1;
    *(f32x4*)red[pg][2][lane] = acc2;
    *(f32x4*)red[pg][3][lane] = acc3;
  }
  __syncthreads();
  if (gsel == 0) {
    acc0 += *(const f32x4*)red[pg][0][lane];
    acc1 += *(const f32x4*)red[pg][1][lane];
    acc2 += *(const f32x4*)red[pg][2][lane];
    acc3 += *(const f32x4*)red[pg][3][lane];
    float* ob = out + pixin + kq * 4;
    const int colb = lane & 15;
#pragma unroll
    for (int r = 0; r < 4; ++r) {
      ob[((b*64 +      colb) << 14) + r] = acc0[r];
      ob[((b*64 + 16 + colb) << 14) + r] = acc1[r];
      ob[((b*64 + 32 + colb) << 14) + r] = acc2[r];
      ob[((b*64 + 48 + colb) << 14) + r] = acc3[r];
    }
  }
}

extern "C" void kernel_launch(void* const* d_in, const int* in_sizes, int n_in,
                              void* d_out, int out_size, void* d_ws, size_t ws_size,
                              hipStream_t stream) {
  const float* x     = (const float*)d_in[0];
  const float* w_off = (const float*)d_in[1];
  const float* w_def = (const float*)d_in[2];
  float* out = (float*)d_out;

  char* ws = (char*)d_ws;
  ushort* xt     = (ushort*)ws;
  float*  off    = (float*)(ws + XT_BYTES);
  ushort* pk_def = (ushort*)(ws + XT_BYTES + OFF_BYTES);
  ushort* pk_off = (ushort*)(ws + XT_BYTES + OFF_BYTES + PKDEF_BYTES);

  transpose_cast<<<1024, 256, 0, stream>>>(x, xt);
  prep_pack<<<32, 256, 0, stream>>>(w_off, w_def, pk_def, pk_off);
  offs_conv_mfma<<<1024, 512, 0, stream>>>(xt, pk_off, off);
  deform_main_mfma<<<1024, 512, 0, stream>>>(xt, pk_def, off, out);
}

// Round 7
// 59.463 us; speedup vs baseline: 1.4212x; 1.3852x over previous
//
#include <hip/hip_runtime.h>
#include <hip/hip_bf16.h>

typedef short bf16x8 __attribute__((ext_vector_type(8)));
typedef float f32x4  __attribute__((ext_vector_type(4)));

#define Bn 4
#define Cn 64
#define Hn 128
#define Wn 128
#define HWn 16384

// ws layout (bytes):
//   xt     [B][H][seg0..7][W][8ch] bf16 @ 0        (8 MB)
//   off    [B][36][H][W] f32   @ XT_BYTES
//   pk_def [18][4][64][8] bf16 @ XT+OFF
//   pk_off [18][3][64][8] bf16 @ XT+OFF+PKDEF
#define XT_BYTES    (Bn*HWn*Cn*2)
#define OFF_BYTES   (Bn*36*HWn*4)
#define PKDEF_BYTES (18*4*64*8*2)

static __device__ __forceinline__ unsigned pk_bf16(float lo, float hi) {
  union { __hip_bfloat162 h; unsigned u; } cv;
  cv.h = __float22bfloat162_rn(make_float2(lo, hi));
  return cv.u;
}
static __device__ __forceinline__ float blo(unsigned u) { return __uint_as_float(u << 16); }
static __device__ __forceinline__ float bhi(unsigned u) { return __uint_as_float(u & 0xffff0000u); }

// ---- x: NCHW f32 -> [b][y][seg][x][8] bf16
__global__ __launch_bounds__(256) void transpose_cast(const float* __restrict__ x,
                                                      ushort* __restrict__ xt) {
  __shared__ float tile[64][65];
  const int t = threadIdx.x;
  const int blk = blockIdx.x;            // 1024 = B * 256
  const int b = blk >> 8;
  const int pix0 = (blk & 255) * 64;
  const int y = pix0 >> 7, x0 = pix0 & 127;
  const float* xb = x + (b * Cn) * HWn + pix0;
#pragma unroll
  for (int q = 0; q < 16; ++q) {
    int idx = q * 256 + t;
    int c = idx >> 6, p = idx & 63;
    tile[c][p] = xb[c * HWn + p];
  }
  __syncthreads();
  const int p = t & 63, cg = t >> 6;
#pragma unroll
  for (int half = 0; half < 2; ++half) {
    const int seg = cg * 2 + half;
    unsigned u[4];
#pragma unroll
    for (int j = 0; j < 4; ++j)
      u[j] = pk_bf16(tile[seg * 8 + 2 * j][p], tile[seg * 8 + 2 * j + 1][p]);
    uint4 v = {u[0], u[1], u[2], u[3]};
    *(uint4*)(xt + (((((b << 7) + y) << 3) + seg) * 128 + x0 + p) * 8) = v;
  }
}

// ---- pack weights as MFMA B-fragments (layout-independent)
__global__ __launch_bounds__(256) void prep_pack(const float* __restrict__ w_off,
                                                 const float* __restrict__ w_def,
                                                 ushort* __restrict__ pk_def,
                                                 ushort* __restrict__ pk_off) {
  const int t = blockIdx.x * 256 + threadIdx.x;
  if (t < 4608) {                        // 18*4*64
    int lane = t & 63, oc = (t >> 6) & 3, s = t >> 8;
    int g = s / 9, k = s % 9;
    int o = oc * 16 + (lane & 15);
    int cb = g * 32 + (lane >> 4) * 8;
    unsigned u[4];
#pragma unroll
    for (int j = 0; j < 4; ++j)
      u[j] = pk_bf16(w_def[(o * Cn + cb + 2 * j) * 9 + k],
                     w_def[(o * Cn + cb + 2 * j + 1) * 9 + k]);
    uint4 v = {u[0], u[1], u[2], u[3]};
    *(uint4*)(pk_def + t * 8) = v;
  } else if (t < 8064) {                 // + 18*3*64
    int t2 = t - 4608;
    int lane = t2 & 63, r = t2 >> 6;     // r = s*3 + oc
    int oc = r % 3, s = r / 3;
    int k = s >> 1, chalf = s & 1;
    int o = oc * 16 + (lane & 15);
    int cb = chalf * 32 + (lane >> 4) * 8;
    unsigned u[4];
#pragma unroll
    for (int j = 0; j < 4; ++j) {
      float lo = (o < 36) ? w_off[(o * Cn + cb + 2 * j) * 9 + k] : 0.f;
      float hi = (o < 36) ? w_off[(o * Cn + cb + 2 * j + 1) * 9 + k] : 0.f;
      u[j] = pk_bf16(lo, hi);
    }
    uint4 v = {u[0], u[1], u[2], u[3]};
    *(uint4*)(pk_off + (r * 64 + lane) * 8) = v;
  }
}

// ---- offset conv: 16x4 pixel tile per block, LDS-staged input, 2-way K-split.
__global__ __launch_bounds__(512, 8) void offs_conv_mfma(const ushort* __restrict__ xt,
                                                         const ushort* __restrict__ pk_off,
                                                         float* __restrict__ off) {
  __shared__ ushort tile[6 * 18 * 72];   // 15,552 B; reduce buffer aliases later
  const int lane = threadIdx.x & 63;
  const int wid = threadIdx.x >> 6;
  const int pg = wid >> 1, ssel = wid & 1;
  int bid = blockIdx.x;
  bid = (bid & 7) * 128 + (bid >> 3);    // XCD swizzle (1024 % 8 == 0, bijective)
  const int b  = bid >> 8;
  const int ty = (bid >> 3) & 31;
  const int tx = bid & 7;
  const int y0t = ty * 4, x0t = tx * 16;
  const int TLY = max(0, y0t - 1), THY = min(127, y0t + 4);
  const int TLX = max(0, x0t - 1), THX = min(127, x0t + 16);
  const int Hd = THY - TLY + 1, Wd = THX - TLX + 1;

  { // stage [Hd][Wd][64ch] -> LDS, coalesced runs of (y',seg)
    const int xq = threadIdx.x & 31;
    const int r0 = threadIdx.x >> 5;
    const int nr = Hd * 8;
    for (int rr = r0; rr < nr; rr += 16) {
      const int yq = rr >> 3, seg = rr & 7;
      if (xq < Wd) {
        const ushort* src = xt + ((((b << 7) + TLY + yq) << 3) + seg) * 1024 + (TLX + xq) * 8;
        *(uint4*)&tile[(yq * 18 + xq) * 72 + seg * 8] = *(const uint4*)src;
      }
    }
  }
  __syncthreads();

  const int h = y0t + pg;
  const int p = lane & 15, kq = lane >> 4;
  const int w_ = x0t + p;
  const int pixin = (h << 7) + x0t;

  f32x4 acc0 = {0,0,0,0}, acc1 = {0,0,0,0}, acc2 = {0,0,0,0};
  const bf16x8* pB = (const bf16x8*)pk_off;

#pragma unroll
  for (int j = 0; j < 9; ++j) {
    const int s = ssel * 9 + j;
    const int k = s >> 1, chalf = s & 1;
    int y = h + k / 3 - 1, xx = w_ + k % 3 - 1;
    bool valid = ((unsigned)y < 128u) && ((unsigned)xx < 128u);
    int yc = min(max(y, 0), 127), xc = min(max(xx, 0), 127);
    const int seg = chalf * 4 + kq;
    uint4 t_ = *(const uint4*)&tile[((yc - TLY) * 18 + (xc - TLX)) * 72 + seg * 8];
    if (!valid) { t_.x = 0; t_.y = 0; t_.z = 0; t_.w = 0; }
    union { uint4 u; bf16x8 v; } A; A.u = t_;
    acc0 = __builtin_amdgcn_mfma_f32_16x16x32_bf16(A.v, pB[(s*3 + 0)*64 + lane], acc0, 0,0,0);
    acc1 = __builtin_amdgcn_mfma_f32_16x16x32_bf16(A.v, pB[(s*3 + 1)*64 + lane], acc1, 0,0,0);
    acc2 = __builtin_amdgcn_mfma_f32_16x16x32_bf16(A.v, pB[(s*3 + 2)*64 + lane], acc2, 0,0,0);
  }

  __syncthreads();                       // all waves done with tile
  float* red = (float*)tile;             // [4][3][64][4] f32 = 12 KB
  if (ssel == 1) {
    *(f32x4*)&red[((pg * 3 + 0) * 64 + lane) * 4] = acc0;
    *(f32x4*)&red[((pg * 3 + 1) * 64 + lane) * 4] = acc1;
    *(f32x4*)&red[((pg * 3 + 2) * 64 + lane) * 4] = acc2;
  }
  __syncthreads();
  if (ssel == 0) {
    acc0 += *(const f32x4*)&red[((pg * 3 + 0) * 64 + lane) * 4];
    acc1 += *(const f32x4*)&red[((pg * 3 + 1) * 64 + lane) * 4];
    acc2 += *(const f32x4*)&red[((pg * 3 + 2) * 64 + lane) * 4];
    float* ob = off + pixin + kq * 4;
    const int colb = lane & 15;
#pragma unroll
    for (int r = 0; r < 4; ++r) {
      ob[((b*36 +      colb) << 14) + r] = acc0[r];
      ob[((b*36 + 16 + colb) << 14) + r] = acc1[r];
      if (colb < 4) ob[((b*36 + 32 + colb) << 14) + r] = acc2[r];
    }
  }
}

// ---- main deformable conv: 16x4 tile, LDS-staged halo +/-4, global fallback.
__global__ __launch_bounds__(512, 6) void deform_main_mfma(const ushort* __restrict__ xt,
                                                           const ushort* __restrict__ pk_def,
                                                           const float* __restrict__ off,
                                                           float* __restrict__ out) {
  __shared__ ushort tile[13 * 25 * 72];  // 46,800 B; reduce buffer aliases later
  const int lane = threadIdx.x & 63;
  const int wid = threadIdx.x >> 6;
  const int pg = wid >> 1, gsel = wid & 1;
  int bid = blockIdx.x;
  bid = (bid & 7) * 128 + (bid >> 3);    // XCD swizzle
  const int b  = bid >> 8;
  const int ty = (bid >> 3) & 31;
  const int tx = bid & 7;
  const int y0t = ty * 4, x0t = tx * 16;
  const int TLY = max(0, y0t - 4), THY = min(127, y0t + 8);
  const int TLX = max(0, x0t - 4), THX = min(127, x0t + 20);
  const int Hd = THY - TLY + 1, Wd = THX - TLX + 1;

  { // stage [Hd][Wd][64ch] -> LDS
    const int xq = threadIdx.x & 31;
    const int r0 = threadIdx.x >> 5;
    const int nr = Hd * 8;
    for (int rr = r0; rr < nr; rr += 16) {
      const int yq = rr >> 3, seg = rr & 7;
      if (xq < Wd) {
        const ushort* src = xt + ((((b << 7) + TLY + yq) << 3) + seg) * 1024 + (TLX + xq) * 8;
        *(uint4*)&tile[(yq * 25 + xq) * 72 + seg * 8] = *(const uint4*)src;
      }
    }
  }

  const int h = y0t + pg;
  const int p = lane & 15, kq = lane >> 4;
  const int w_ = x0t + p;
  const int pixin = (h << 7) + x0t;
  const int su = gsel * 4 + kq;

  // preload this wave's 18 offset channels (overlaps staging)
  const float* offb = off + ((b * 36 + gsel * 18) << 14) + pixin + p;
  float offv[18];
#pragma unroll
  for (int j = 0; j < 18; ++j) offv[j] = offb[j << 14];

  __syncthreads();

  f32x4 acc0={0,0,0,0}, acc1={0,0,0,0}, acc2={0,0,0,0}, acc3={0,0,0,0};
  const bf16x8* pB = (const bf16x8*)pk_def;

#pragma unroll
  for (int j = 0; j < 9; ++j) {
    const int k = j;
    float py = offv[2*j]   + (float)(h  + k / 3 - 1);
    float px = offv[2*j+1] + (float)(w_ + k % 3 - 1);
    float fy = floorf(py), fx = floorf(px);
    int y0 = (int)fy, x0 = (int)fx;
    float dy = py - fy, dx = px - fx;

    bool vy0 = (y0 >= 0) && (y0 < Hn);
    bool vy1 = (y0 >= -1) && (y0 < Hn - 1);
    bool vx0 = (x0 >= 0) && (x0 < Wn);
    bool vx1 = (x0 >= -1) && (x0 < Wn - 1);
    float omdy = 1.f - dy, omdx = 1.f - dx;
    float w00 = (vy0 && vx0) ? omdy * omdx : 0.f;
    float w01 = (vy0 && vx1) ? omdy * dx   : 0.f;
    float w10 = (vy1 && vx0) ? dy * omdx   : 0.f;
    float w11 = (vy1 && vx1) ? dy * dx     : 0.f;

    int iy0 = min(max(y0, 0), Hn - 1), iy1 = min(max(y0 + 1, 0), Hn - 1);
    int ix0 = min(max(x0, 0), Wn - 1), ix1 = min(max(x0 + 1, 0), Wn - 1);

    uint4 c00, c01, c10, c11;
    bool intile = (iy0 >= TLY) && (iy1 <= THY) && (ix0 >= TLX) && (ix1 <= THX);
    if (__all((int)intile)) {            // fast path: LDS (covers ~97% of wave-taps)
      const int ly0 = iy0 - TLY, ly1 = iy1 - TLY;
      const int lx0 = ix0 - TLX, lx1 = ix1 - TLX;
      c00 = *(const uint4*)&tile[(ly0 * 25 + lx0) * 72 + su * 8];
      c01 = *(const uint4*)&tile[(ly0 * 25 + lx1) * 72 + su * 8];
      c10 = *(const uint4*)&tile[(ly1 * 25 + lx0) * 72 + su * 8];
      c11 = *(const uint4*)&tile[(ly1 * 25 + lx1) * 72 + su * 8];
    } else {                             // rare fallback: global gather
      const int r0g = ((((b << 7) + iy0) << 3) + su) * 128;
      const int r1g = ((((b << 7) + iy1) << 3) + su) * 128;
      c00 = *(const uint4*)(xt + (r0g + ix0) * 8);
      c01 = *(const uint4*)(xt + (r0g + ix1) * 8);
      c10 = *(const uint4*)(xt + (r1g + ix0) * 8);
      c11 = *(const uint4*)(xt + (r1g + ix1) * 8);
    }

    unsigned au[4];
#define BILC(comp, idx)                                                        \
    { float l = w00 * blo(c00.comp); l = fmaf(w01, blo(c01.comp), l);          \
      l = fmaf(w10, blo(c10.comp), l); l = fmaf(w11, blo(c11.comp), l);        \
      float hh = w00 * bhi(c00.comp); hh = fmaf(w01, bhi(c01.comp), hh);       \
      hh = fmaf(w10, bhi(c10.comp), hh); hh = fmaf(w11, bhi(c11.comp), hh);    \
      au[idx] = pk_bf16(l, hh); }
    BILC(x, 0) BILC(y, 1) BILC(z, 2) BILC(w, 3)
#undef BILC
    union { uint4 u; bf16x8 v; } A;
    A.u.x = au[0]; A.u.y = au[1]; A.u.z = au[2]; A.u.w = au[3];

    const int s = gsel * 9 + j;
    acc0 = __builtin_amdgcn_mfma_f32_16x16x32_bf16(A.v, pB[(s*4 + 0)*64 + lane], acc0, 0,0,0);
    acc1 = __builtin_amdgcn_mfma_f32_16x16x32_bf16(A.v, pB[(s*4 + 1)*64 + lane], acc1, 0,0,0);
    acc2 = __builtin_amdgcn_mfma_f32_16x16x32_bf16(A.v, pB[(s*4 + 2)*64 + lane], acc2, 0,0,0);
    acc3 = __builtin_amdgcn_mfma_f32_16x16x32_bf16(A.v, pB[(s*4 + 3)*64 + lane], acc3, 0,0,0);
  }

  __syncthreads();                       // all waves done with tile
  float* red = (float*)tile;             // [4][4][64][4] f32 = 16 KB
  if (gsel == 1) {
    *(f32x4*)&red[((pg * 4 + 0) * 64 + lane) * 4] = acc0;
    *(f32x4*)&red[((pg * 4 + 1) * 64 + lane) * 4] = acc1;
    *(f32x4*)&red[((pg * 4 + 2) * 64 + lane) * 4] = acc2;
    *(f32x4*)&red[((pg * 4 + 3) * 64 + lane) * 4] = acc3;
  }
  __syncthreads();
  if (gsel == 0) {
    acc0 += *(const f32x4*)&red[((pg * 4 + 0) * 64 + lane) * 4];
    acc1 += *(const f32x4*)&red[((pg * 4 + 1) * 64 + lane) * 4];
    acc2 += *(const f32x4*)&red[((pg * 4 + 2) * 64 + lane) * 4];
    acc3 += *(const f32x4*)&red[((pg * 4 + 3) * 64 + lane) * 4];
    float* ob = out + pixin + kq * 4;
    const int colb = lane & 15;
#pragma unroll
    for (int r = 0; r < 4; ++r) {
      ob[((b*64 +      colb) << 14) + r] = acc0[r];
      ob[((b*64 + 16 + colb) << 14) + r] = acc1[r];
      ob[((b*64 + 32 + colb) << 14) + r] = acc2[r];
      ob[((b*64 + 48 + colb) << 14) + r] = acc3[r];
    }
  }
}

extern "C" void kernel_launch(void* const* d_in, const int* in_sizes, int n_in,
                              void* d_out, int out_size, void* d_ws, size_t ws_size,
                              hipStream_t stream) {
  const float* x     = (const float*)d_in[0];
  const float* w_off = (const float*)d_in[1];
  const float* w_def = (const float*)d_in[2];
  float* out = (float*)d_out;

  char* ws = (char*)d_ws;
  ushort* xt     = (ushort*)ws;
  float*  off    = (float*)(ws + XT_BYTES);
  ushort* pk_def = (ushort*)(ws + XT_BYTES + OFF_BYTES);
  ushort* pk_off = (ushort*)(ws + XT_BYTES + OFF_BYTES + PKDEF_BYTES);

  transpose_cast<<<1024, 256, 0, stream>>>(x, xt);
  prep_pack<<<32, 256, 0, stream>>>(w_off, w_def, pk_def, pk_off);
  offs_conv_mfma<<<1024, 512, 0, stream>>>(xt, pk_off, off);
  deform_main_mfma<<<1024, 512, 0, stream>>>(xt, pk_def, off, out);
}

// Round 8
// 54.416 us; speedup vs baseline: 1.5530x; 1.0927x over previous
//
#include <hip/hip_runtime.h>
#include <hip/hip_bf16.h>

typedef short bf16x8 __attribute__((ext_vector_type(8)));
typedef float f32x4  __attribute__((ext_vector_type(4)));

#define Bn 4
#define Cn 64
#define Hn 128
#define Wn 128
#define HWn 16384

// ws layout (bytes):
//   xt     [B][H][seg0..7][W][8ch] bf16 @ 0   (8 MB)
//   pk_def [18][4][64][8] bf16 @ XT_BYTES     B-frags, main conv
//   pk_off [18][3][64][8] bf16 @ +PKDEF       B-frags, offset conv
#define XT_BYTES    (Bn*HWn*Cn*2)
#define PKDEF_BYTES (18*4*64*8*2)

static __device__ __forceinline__ unsigned pk_bf16(float lo, float hi) {
  union { __hip_bfloat162 h; unsigned u; } cv;
  cv.h = __float22bfloat162_rn(make_float2(lo, hi));
  return cv.u;
}
static __device__ __forceinline__ float blo(unsigned u) { return __uint_as_float(u << 16); }
static __device__ __forceinline__ float bhi(unsigned u) { return __uint_as_float(u & 0xffff0000u); }

// ---- x: NCHW f32 -> [b][y][seg][x][8] bf16
__global__ __launch_bounds__(256) void transpose_cast(const float* __restrict__ x,
                                                      ushort* __restrict__ xt) {
  __shared__ float tile[64][65];
  const int t = threadIdx.x;
  const int blk = blockIdx.x;            // 1024 = B * 256
  const int b = blk >> 8;
  const int pix0 = (blk & 255) * 64;
  const int y = pix0 >> 7, x0 = pix0 & 127;
  const float* xb = x + (b * Cn) * HWn + pix0;
#pragma unroll
  for (int q = 0; q < 16; ++q) {
    int idx = q * 256 + t;
    int c = idx >> 6, p = idx & 63;
    tile[c][p] = xb[c * HWn + p];
  }
  __syncthreads();
  const int p = t & 63, cg = t >> 6;
#pragma unroll
  for (int half = 0; half < 2; ++half) {
    const int seg = cg * 2 + half;
    unsigned u[4];
#pragma unroll
    for (int j = 0; j < 4; ++j)
      u[j] = pk_bf16(tile[seg * 8 + 2 * j][p], tile[seg * 8 + 2 * j + 1][p]);
    uint4 v = {u[0], u[1], u[2], u[3]};
    *(uint4*)(xt + (((((b << 7) + y) << 3) + seg) * 128 + x0 + p) * 8) = v;
  }
}

// ---- pack weights as MFMA B-fragments
__global__ __launch_bounds__(256) void prep_pack(const float* __restrict__ w_off,
                                                 const float* __restrict__ w_def,
                                                 ushort* __restrict__ pk_def,
                                                 ushort* __restrict__ pk_off) {
  const int t = blockIdx.x * 256 + threadIdx.x;
  if (t < 4608) {                        // 18*4*64
    int lane = t & 63, oc = (t >> 6) & 3, s = t >> 8;
    int g = s / 9, k = s % 9;
    int o = oc * 16 + (lane & 15);
    int cb = g * 32 + (lane >> 4) * 8;
    unsigned u[4];
#pragma unroll
    for (int j = 0; j < 4; ++j)
      u[j] = pk_bf16(w_def[(o * Cn + cb + 2 * j) * 9 + k],
                     w_def[(o * Cn + cb + 2 * j + 1) * 9 + k]);
    uint4 v = {u[0], u[1], u[2], u[3]};
    *(uint4*)(pk_def + t * 8) = v;
  } else if (t < 8064) {                 // + 18*3*64
    int t2 = t - 4608;
    int lane = t2 & 63, r = t2 >> 6;     // r = s*3 + oc
    int oc = r % 3, s = r / 3;
    int k = s >> 1, chalf = s & 1;
    int o = oc * 16 + (lane & 15);
    int cb = chalf * 32 + (lane >> 4) * 8;
    unsigned u[4];
#pragma unroll
    for (int j = 0; j < 4; ++j) {
      float lo = (o < 36) ? w_off[(o * Cn + cb + 2 * j) * 9 + k] : 0.f;
      float hi = (o < 36) ? w_off[(o * Cn + cb + 2 * j + 1) * 9 + k] : 0.f;
      u[j] = pk_bf16(lo, hi);
    }
    uint4 v = {u[0], u[1], u[2], u[3]};
    *(uint4*)(pk_off + (r * 64 + lane) * 8) = v;
  }
}

// ---- FUSED: stage tile -> offset conv (MFMA, LDS-resident result) ->
//             deformable gather (LDS fast path) -> main MFMA -> reduce/write.
// 16x4 pixel tile, 8 waves = 4 pixel-rows x 2 group-halves (gsel).
__global__ __launch_bounds__(512, 4) void deform_fused(const ushort* __restrict__ xt,
                                                       const ushort* __restrict__ pk_def,
                                                       const ushort* __restrict__ pk_off,
                                                       float* __restrict__ out) {
  __shared__ ushort tile[13 * 25 * 72];  // 46,800 B (reduce buffer aliases later)
  __shared__ float off_lds[4][36][17];   // 9,792 B  (padded: 17 breaks bank stride)
  const int lane = threadIdx.x & 63;
  const int wid = threadIdx.x >> 6;
  const int pg = wid >> 1, gsel = wid & 1;
  int bid = blockIdx.x;
  bid = (bid & 7) * 128 + (bid >> 3);    // bijective XCD swizzle (1024 % 8 == 0)
  const int b  = bid >> 8;
  const int ty = (bid >> 3) & 31;
  const int tx = bid & 7;
  const int y0t = ty * 4, x0t = tx * 16;
  const int TLY = max(0, y0t - 4), THY = min(127, y0t + 8);
  const int TLX = max(0, x0t - 4), THX = min(127, x0t + 20);
  const int Hd = THY - TLY + 1, Wd = THX - TLX + 1;

  { // stage [Hd][Wd][64ch] -> LDS (coalesced)
    const int xq = threadIdx.x & 31;
    const int r0 = threadIdx.x >> 5;
    const int nr = Hd * 8;
    for (int rr = r0; rr < nr; rr += 16) {
      const int yq = rr >> 3, seg = rr & 7;
      if (xq < Wd) {
        const ushort* src = xt + ((((b << 7) + TLY + yq) << 3) + seg) * 1024 + (TLX + xq) * 8;
        *(uint4*)&tile[(yq * 25 + xq) * 72 + seg * 8] = *(const uint4*)src;
      }
    }
  }
  __syncthreads();

  const int h = y0t + pg;
  const int p = lane & 15, kq = lane >> 4;
  const int w_ = x0t + p;
  const int pixin = (h << 7) + x0t;
  const int su = gsel * 4 + kq;
  const int colb = lane & 15;

  // ---- phase 1: offset conv for this block's 64 pixels, from the staged tile.
  // N-split across the wave pair: gsel0 -> off ch 0-15 & 32-35, gsel1 -> 16-31.
  {
    f32x4 oa0 = {0,0,0,0}, oa1 = {0,0,0,0}, oa2 = {0,0,0,0};
    const bf16x8* pBo = (const bf16x8*)pk_off;
#pragma unroll
    for (int s = 0; s < 18; ++s) {
      const int k = s >> 1, chalf = s & 1;
      int y = h + k / 3 - 1, xx = w_ + k % 3 - 1;
      bool valid = ((unsigned)y < 128u) && ((unsigned)xx < 128u);
      int yc = min(max(y, 0), 127), xc = min(max(xx, 0), 127);
      const int seg = chalf * 4 + kq;
      uint4 t_ = *(const uint4*)&tile[((yc - TLY) * 25 + (xc - TLX)) * 72 + seg * 8];
      if (!valid) { t_.x = 0; t_.y = 0; t_.z = 0; t_.w = 0; }
      union { uint4 u; bf16x8 v; } A; A.u = t_;
      if (gsel == 0) {
        oa0 = __builtin_amdgcn_mfma_f32_16x16x32_bf16(A.v, pBo[(s*3 + 0)*64 + lane], oa0, 0,0,0);
        oa2 = __builtin_amdgcn_mfma_f32_16x16x32_bf16(A.v, pBo[(s*3 + 2)*64 + lane], oa2, 0,0,0);
      } else {
        oa1 = __builtin_amdgcn_mfma_f32_16x16x32_bf16(A.v, pBo[(s*3 + 1)*64 + lane], oa1, 0,0,0);
      }
    }
    // D: col = lane&15 = offset channel (within 16-group), row = kq*4+r = pixel x
    if (gsel == 0) {
#pragma unroll
      for (int r = 0; r < 4; ++r) {
        off_lds[pg][colb][kq * 4 + r] = oa0[r];
        if (colb < 4) off_lds[pg][32 + colb][kq * 4 + r] = oa2[r];
      }
    } else {
#pragma unroll
      for (int r = 0; r < 4; ++r) off_lds[pg][16 + colb][kq * 4 + r] = oa1[r];
    }
  }
  __syncthreads();

  // this wave's 18 offset channels for its pixel (LDS, broadcast across kq)
  float offv[18];
#pragma unroll
  for (int j = 0; j < 18; ++j) offv[j] = off_lds[pg][gsel * 18 + j][p];

  // ---- phase 2: deformable gather (LDS fast path, global fallback) + main MFMA
  f32x4 acc0={0,0,0,0}, acc1={0,0,0,0}, acc2={0,0,0,0}, acc3={0,0,0,0};
  const bf16x8* pB = (const bf16x8*)pk_def;

#pragma unroll
  for (int j = 0; j < 9; ++j) {
    const int k = j;
    float py = offv[2*j]   + (float)(h  + k / 3 - 1);
    float px = offv[2*j+1] + (float)(w_ + k % 3 - 1);
    float fy = floorf(py), fx = floorf(px);
    int y0 = (int)fy, x0 = (int)fx;
    float dy = py - fy, dx = px - fx;

    bool vy0 = (y0 >= 0) && (y0 < Hn);
    bool vy1 = (y0 >= -1) && (y0 < Hn - 1);
    bool vx0 = (x0 >= 0) && (x0 < Wn);
    bool vx1 = (x0 >= -1) && (x0 < Wn - 1);
    float omdy = 1.f - dy, omdx = 1.f - dx;
    float w00 = (vy0 && vx0) ? omdy * omdx : 0.f;
    float w01 = (vy0 && vx1) ? omdy * dx   : 0.f;
    float w10 = (vy1 && vx0) ? dy * omdx   : 0.f;
    float w11 = (vy1 && vx1) ? dy * dx     : 0.f;

    int iy0 = min(max(y0, 0), Hn - 1), iy1 = min(max(y0 + 1, 0), Hn - 1);
    int ix0 = min(max(x0, 0), Wn - 1), ix1 = min(max(x0 + 1, 0), Wn - 1);

    uint4 c00, c01, c10, c11;
    bool intile = (iy0 >= TLY) && (iy1 <= THY) && (ix0 >= TLX) && (ix1 <= THX);
    if (__all((int)intile)) {            // fast path: LDS
      const int ly0 = iy0 - TLY, ly1 = iy1 - TLY;
      const int lx0 = ix0 - TLX, lx1 = ix1 - TLX;
      c00 = *(const uint4*)&tile[(ly0 * 25 + lx0) * 72 + su * 8];
      c01 = *(const uint4*)&tile[(ly0 * 25 + lx1) * 72 + su * 8];
      c10 = *(const uint4*)&tile[(ly1 * 25 + lx0) * 72 + su * 8];
      c11 = *(const uint4*)&tile[(ly1 * 25 + lx1) * 72 + su * 8];
    } else {                             // fallback: global gather
      const int r0g = ((((b << 7) + iy0) << 3) + su) * 128;
      const int r1g = ((((b << 7) + iy1) << 3) + su) * 128;
      c00 = *(const uint4*)(xt + (r0g + ix0) * 8);
      c01 = *(const uint4*)(xt + (r0g + ix1) * 8);
      c10 = *(const uint4*)(xt + (r1g + ix0) * 8);
      c11 = *(const uint4*)(xt + (r1g + ix1) * 8);
    }

    unsigned au[4];
#define BILC(comp, idx)                                                        \
    { float l = w00 * blo(c00.comp); l = fmaf(w01, blo(c01.comp), l);          \
      l = fmaf(w10, blo(c10.comp), l); l = fmaf(w11, blo(c11.comp), l);        \
      float hh = w00 * bhi(c00.comp); hh = fmaf(w01, bhi(c01.comp), hh);       \
      hh = fmaf(w10, bhi(c10.comp), hh); hh = fmaf(w11, bhi(c11.comp), hh);    \
      au[idx] = pk_bf16(l, hh); }
    BILC(x, 0) BILC(y, 1) BILC(z, 2) BILC(w, 3)
#undef BILC
    union { uint4 u; bf16x8 v; } A;
    A.u.x = au[0]; A.u.y = au[1]; A.u.z = au[2]; A.u.w = au[3];

    const int s = gsel * 9 + j;
    acc0 = __builtin_amdgcn_mfma_f32_16x16x32_bf16(A.v, pB[(s*4 + 0)*64 + lane], acc0, 0,0,0);
    acc1 = __builtin_amdgcn_mfma_f32_16x16x32_bf16(A.v, pB[(s*4 + 1)*64 + lane], acc1, 0,0,0);
    acc2 = __builtin_amdgcn_mfma_f32_16x16x32_bf16(A.v, pB[(s*4 + 2)*64 + lane], acc2, 0,0,0);
    acc3 = __builtin_amdgcn_mfma_f32_16x16x32_bf16(A.v, pB[(s*4 + 3)*64 + lane], acc3, 0,0,0);
  }

  __syncthreads();                       // all waves done with tile
  float* red = (float*)tile;             // [4][4][64][4] f32 = 16 KB (aliases tile)
  if (gsel == 1) {
    *(f32x4*)&red[((pg * 4 + 0) * 64 + lane) * 4] = acc0;
    *(f32x4*)&red[((pg * 4 + 1) * 64 + lane) * 4] = acc1;
    *(f32x4*)&red[((pg * 4 + 2) * 64 + lane) * 4] = acc2;
    *(f32x4*)&red[((pg * 4 + 3) * 64 + lane) * 4] = acc3;
  }
  __syncthreads();
  if (gsel == 0) {
    acc0 += *(const f32x4*)&red[((pg * 4 + 0) * 64 + lane) * 4];
    acc1 += *(const f32x4*)&red[((pg * 4 + 1) * 64 + lane) * 4];
    acc2 += *(const f32x4*)&red[((pg * 4 + 2) * 64 + lane) * 4];
    acc3 += *(const f32x4*)&red[((pg * 4 + 3) * 64 + lane) * 4];
    float* ob = out + pixin + kq * 4;
#pragma unroll
    for (int r = 0; r < 4; ++r) {
      ob[((b*64 +      colb) << 14) + r] = acc0[r];
      ob[((b*64 + 16 + colb) << 14) + r] = acc1[r];
      ob[((b*64 + 32 + colb) << 14) + r] = acc2[r];
      ob[((b*64 + 48 + colb) << 14) + r] = acc3[r];
    }
  }
}

extern "C" void kernel_launch(void* const* d_in, const int* in_sizes, int n_in,
                              void* d_out, int out_size, void* d_ws, size_t ws_size,
                              hipStream_t stream) {
  const float* x     = (const float*)d_in[0];
  const float* w_off = (const float*)d_in[1];
  const float* w_def = (const float*)d_in[2];
  float* out = (float*)d_out;

  char* ws = (char*)d_ws;
  ushort* xt     = (ushort*)ws;
  ushort* pk_def = (ushort*)(ws + XT_BYTES);
  ushort* pk_off = (ushort*)(ws + XT_BYTES + PKDEF_BYTES);

  transpose_cast<<<1024, 256, 0, stream>>>(x, xt);
  prep_pack<<<32, 256, 0, stream>>>(w_off, w_def, pk_def, pk_off);
  deform_fused<<<1024, 512, 0, stream>>>(xt, pk_def, pk_off, out);
}

// Round 9
// 53.697 us; speedup vs baseline: 1.5738x; 1.0134x over previous
//
#include <hip/hip_runtime.h>
#include <hip/hip_bf16.h>

typedef _Float16 f16x8 __attribute__((ext_vector_type(8)));
typedef _Float16 f16x2 __attribute__((ext_vector_type(2)));
typedef float f32x4  __attribute__((ext_vector_type(4)));

#define Bn 4
#define Cn 64
#define Hn 128
#define Wn 128
#define HWn 16384

// ws layout (bytes):
//   xt     [B][H][seg0..7][W][8ch] f16 @ 0   (8 MB)
//   pk_def [18][4][64][8] f16 @ XT_BYTES     B-frags, main conv
//   pk_off [18][3][64][8] f16 @ +PKDEF       B-frags, offset conv
#define XT_BYTES    (Bn*HWn*Cn*2)
#define PKDEF_BYTES (18*4*64*8*2)

static __device__ __forceinline__ unsigned pk_f16(float lo, float hi) {
  union { _Float16 h[2]; unsigned u; } cv;
  cv.h[0] = (_Float16)lo; cv.h[1] = (_Float16)hi;
  return cv.u;
}

// ---- x: NCHW f32 -> [b][y][seg][x][8] f16
__global__ __launch_bounds__(256) void transpose_cast(const float* __restrict__ x,
                                                      ushort* __restrict__ xt) {
  __shared__ float tile[64][65];
  const int t = threadIdx.x;
  const int blk = blockIdx.x;            // 1024 = B * 256
  const int b = blk >> 8;
  const int pix0 = (blk & 255) * 64;
  const int y = pix0 >> 7, x0 = pix0 & 127;
  const float* xb = x + (b * Cn) * HWn + pix0;
#pragma unroll
  for (int q = 0; q < 16; ++q) {
    int idx = q * 256 + t;
    int c = idx >> 6, p = idx & 63;
    tile[c][p] = xb[c * HWn + p];
  }
  __syncthreads();
  const int p = t & 63, cg = t >> 6;
#pragma unroll
  for (int half = 0; half < 2; ++half) {
    const int seg = cg * 2 + half;
    unsigned u[4];
#pragma unroll
    for (int j = 0; j < 4; ++j)
      u[j] = pk_f16(tile[seg * 8 + 2 * j][p], tile[seg * 8 + 2 * j + 1][p]);
    uint4 v = {u[0], u[1], u[2], u[3]};
    *(uint4*)(xt + (((((b << 7) + y) << 3) + seg) * 128 + x0 + p) * 8) = v;
  }
}

// ---- pack weights as MFMA B-fragments (f16)
__global__ __launch_bounds__(256) void prep_pack(const float* __restrict__ w_off,
                                                 const float* __restrict__ w_def,
                                                 ushort* __restrict__ pk_def,
                                                 ushort* __restrict__ pk_off) {
  const int t = blockIdx.x * 256 + threadIdx.x;
  if (t < 4608) {                        // 18*4*64
    int lane = t & 63, oc = (t >> 6) & 3, s = t >> 8;
    int g = s / 9, k = s % 9;
    int o = oc * 16 + (lane & 15);
    int cb = g * 32 + (lane >> 4) * 8;
    unsigned u[4];
#pragma unroll
    for (int j = 0; j < 4; ++j)
      u[j] = pk_f16(w_def[(o * Cn + cb + 2 * j) * 9 + k],
                    w_def[(o * Cn + cb + 2 * j + 1) * 9 + k]);
    uint4 v = {u[0], u[1], u[2], u[3]};
    *(uint4*)(pk_def + t * 8) = v;
  } else if (t < 8064) {                 // + 18*3*64
    int t2 = t - 4608;
    int lane = t2 & 63, r = t2 >> 6;     // r = s*3 + oc
    int oc = r % 3, s = r / 3;
    int k = s >> 1, chalf = s & 1;
    int o = oc * 16 + (lane & 15);
    int cb = chalf * 32 + (lane >> 4) * 8;
    unsigned u[4];
#pragma unroll
    for (int j = 0; j < 4; ++j) {
      float lo = (o < 36) ? w_off[(o * Cn + cb + 2 * j) * 9 + k] : 0.f;
      float hi = (o < 36) ? w_off[(o * Cn + cb + 2 * j + 1) * 9 + k] : 0.f;
      u[j] = pk_f16(lo, hi);
    }
    uint4 v = {u[0], u[1], u[2], u[3]};
    *(uint4*)(pk_off + (r * 64 + lane) * 8) = v;
  }
}

// ---- FUSED kernel: stage f16 tile -> offset conv (MFMA) -> deformable gather
//      (LDS fast path, pk_fma_f16 bilinear) -> main MFMA -> reduce/write.
// 16x4 pixel tile; 8 waves = 4 pixel-rows x 2 group-halves.
// LDS = 43,056 (tile) + 9,792 (off_lds) = 52,848 B -> 3 blocks/CU.
__global__ __launch_bounds__(512, 6) void deform_fused(const ushort* __restrict__ xt,
                                                       const ushort* __restrict__ pk_def,
                                                       const ushort* __restrict__ pk_off,
                                                       float* __restrict__ out) {
  __shared__ ushort tile[13 * 23 * 72];  // 43,056 B (reduce buffer aliases later)
  __shared__ float off_lds[4][36][17];   // 9,792 B
  const int lane = threadIdx.x & 63;
  const int wid = threadIdx.x >> 6;
  const int pg = wid >> 1, gsel = wid & 1;
  int bid = blockIdx.x;
  bid = (bid & 7) * 128 + (bid >> 3);    // bijective XCD swizzle (1024 % 8 == 0)
  const int b  = bid >> 8;
  const int ty = (bid >> 3) & 31;
  const int tx = bid & 7;
  const int y0t = ty * 4, x0t = tx * 16;
  const int TLY = max(0, y0t - 4), THY = min(127, y0t + 8);
  const int TLX = max(0, x0t - 3), THX = min(127, x0t + 19);
  const int Hd = THY - TLY + 1, Wd = THX - TLX + 1;

  { // stage [Hd][Wd][64ch] -> LDS (coalesced)
    const int xq = threadIdx.x & 31;
    const int r0 = threadIdx.x >> 5;
    const int nr = Hd * 8;
    for (int rr = r0; rr < nr; rr += 16) {
      const int yq = rr >> 3, seg = rr & 7;
      if (xq < Wd) {
        const ushort* src = xt + ((((b << 7) + TLY + yq) << 3) + seg) * 1024 + (TLX + xq) * 8;
        *(uint4*)&tile[(yq * 23 + xq) * 72 + seg * 8] = *(const uint4*)src;
      }
    }
  }
  __syncthreads();

  const int h = y0t + pg;
  const int p = lane & 15, kq = lane >> 4;
  const int w_ = x0t + p;
  const int pixin = (h << 7) + x0t;
  const int su = gsel * 4 + kq;
  const int colb = lane & 15;

  // ---- phase 1: offset conv from staged tile.
  // N-split: gsel0 -> channels 0-15 (1 MFMA/slice); gsel1 -> 16-31 & 32-35 (2).
  {
    f32x4 oa0 = {0,0,0,0}, oa1 = {0,0,0,0}, oa2 = {0,0,0,0};
    const f16x8* pBo = (const f16x8*)pk_off;
#pragma unroll
    for (int s = 0; s < 18; ++s) {
      const int k = s >> 1, chalf = s & 1;
      int y = h + k / 3 - 1, xx = w_ + k % 3 - 1;
      bool valid = ((unsigned)y < 128u) && ((unsigned)xx < 128u);
      int yc = min(max(y, 0), 127), xc = min(max(xx, 0), 127);
      const int seg = chalf * 4 + kq;
      uint4 t_ = *(const uint4*)&tile[((yc - TLY) * 23 + (xc - TLX)) * 72 + seg * 8];
      if (!valid) { t_.x = 0; t_.y = 0; t_.z = 0; t_.w = 0; }
      union { uint4 u; f16x8 v; } A; A.u = t_;
      if (gsel == 0) {
        oa0 = __builtin_amdgcn_mfma_f32_16x16x32_f16(A.v, pBo[(s*3 + 0)*64 + lane], oa0, 0,0,0);
      } else {
        oa1 = __builtin_amdgcn_mfma_f32_16x16x32_f16(A.v, pBo[(s*3 + 1)*64 + lane], oa1, 0,0,0);
        oa2 = __builtin_amdgcn_mfma_f32_16x16x32_f16(A.v, pBo[(s*3 + 2)*64 + lane], oa2, 0,0,0);
      }
    }
    // D: col = lane&15 = offset channel (within 16-group), row = kq*4+r = pixel x
    if (gsel == 0) {
#pragma unroll
      for (int r = 0; r < 4; ++r) off_lds[pg][colb][kq * 4 + r] = oa0[r];
    } else {
#pragma unroll
      for (int r = 0; r < 4; ++r) {
        off_lds[pg][16 + colb][kq * 4 + r] = oa1[r];
        if (colb < 4) off_lds[pg][32 + colb][kq * 4 + r] = oa2[r];
      }
    }
  }
  __syncthreads();

  // this wave's 18 offset channels for its pixel (broadcast across kq)
  float offv[18];
#pragma unroll
  for (int j = 0; j < 18; ++j) offv[j] = off_lds[pg][gsel * 18 + j][p];

  // ---- phase 2: deformable gather + packed-f16 bilinear + main MFMA
  f32x4 acc0={0,0,0,0}, acc1={0,0,0,0}, acc2={0,0,0,0}, acc3={0,0,0,0};
  const f16x8* pB = (const f16x8*)pk_def;

#pragma unroll
  for (int j = 0; j < 9; ++j) {
    const int k = j;
    float py = offv[2*j]   + (float)(h  + k / 3 - 1);
    float px = offv[2*j+1] + (float)(w_ + k % 3 - 1);
    float fy = floorf(py), fx = floorf(px);
    int y0 = (int)fy, x0 = (int)fx;
    float dy = py - fy, dx = px - fx;

    bool vy0 = (y0 >= 0) && (y0 < Hn);
    bool vy1 = (y0 >= -1) && (y0 < Hn - 1);
    bool vx0 = (x0 >= 0) && (x0 < Wn);
    bool vx1 = (x0 >= -1) && (x0 < Wn - 1);
    float omdy = 1.f - dy, omdx = 1.f - dx;
    float w00 = (vy0 && vx0) ? omdy * omdx : 0.f;
    float w01 = (vy0 && vx1) ? omdy * dx   : 0.f;
    float w10 = (vy1 && vx0) ? dy * omdx   : 0.f;
    float w11 = (vy1 && vx1) ? dy * dx     : 0.f;

    int iy0 = min(max(y0, 0), Hn - 1), iy1 = min(max(y0 + 1, 0), Hn - 1);
    int ix0 = min(max(x0, 0), Wn - 1), ix1 = min(max(x0 + 1, 0), Wn - 1);

    uint4 c00, c01, c10, c11;
    bool intile = (iy0 >= TLY) && (iy1 <= THY) && (ix0 >= TLX) && (ix1 <= THX);
    if (__all((int)intile)) {            // fast path: LDS
      const int ly0 = iy0 - TLY, ly1 = iy1 - TLY;
      const int lx0 = ix0 - TLX, lx1 = ix1 - TLX;
      c00 = *(const uint4*)&tile[(ly0 * 23 + lx0) * 72 + su * 8];
      c01 = *(const uint4*)&tile[(ly0 * 23 + lx1) * 72 + su * 8];
      c10 = *(const uint4*)&tile[(ly1 * 23 + lx0) * 72 + su * 8];
      c11 = *(const uint4*)&tile[(ly1 * 23 + lx1) * 72 + su * 8];
    } else {                             // fallback: global gather (L2-hot)
      const int r0g = ((((b << 7) + iy0) << 3) + su) * 128;
      const int r1g = ((((b << 7) + iy1) << 3) + su) * 128;
      c00 = *(const uint4*)(xt + (r0g + ix0) * 8);
      c01 = *(const uint4*)(xt + (r0g + ix1) * 8);
      c10 = *(const uint4*)(xt + (r1g + ix0) * 8);
      c11 = *(const uint4*)(xt + (r1g + ix1) * 8);
    }

    // packed-f16 bilinear: result words ARE the f16 MFMA A-fragment
    const _Float16 h00 = (_Float16)w00, h01 = (_Float16)w01;
    const _Float16 h10 = (_Float16)w10, h11 = (_Float16)w11;
    const f16x2 W00 = {h00, h00}, W01 = {h01, h01};
    const f16x2 W10 = {h10, h10}, W11 = {h11, h11};
    union U32H { unsigned u; f16x2 h; };
    union { uint4 u; f16x8 v; } A;
#define BILC(comp, fld)                                                        \
    { U32H a0, a1, a2, a3, r;                                                  \
      a0.u = c00.comp; a1.u = c01.comp; a2.u = c10.comp; a3.u = c11.comp;      \
      r.h = a0.h * W00 + a1.h * W01 + a2.h * W10 + a3.h * W11;                 \
      A.u.fld = r.u; }
    BILC(x, x) BILC(y, y) BILC(z, z) BILC(w, w)
#undef BILC

    const int s = gsel * 9 + j;
    acc0 = __builtin_amdgcn_mfma_f32_16x16x32_f16(A.v, pB[(s*4 + 0)*64 + lane], acc0, 0,0,0);
    acc1 = __builtin_amdgcn_mfma_f32_16x16x32_f16(A.v, pB[(s*4 + 1)*64 + lane], acc1, 0,0,0);
    acc2 = __builtin_amdgcn_mfma_f32_16x16x32_f16(A.v, pB[(s*4 + 2)*64 + lane], acc2, 0,0,0);
    acc3 = __builtin_amdgcn_mfma_f32_16x16x32_f16(A.v, pB[(s*4 + 3)*64 + lane], acc3, 0,0,0);
  }

  __syncthreads();                       // all waves done with tile
  float* red = (float*)tile;             // [4][4][64][4] f32 = 16 KB (aliases tile)
  if (gsel == 1) {
    *(f32x4*)&red[((pg * 4 + 0) * 64 + lane) * 4] = acc0;
    *(f32x4*)&red[((pg * 4 + 1) * 64 + lane) * 4] = acc1;
    *(f32x4*)&red[((pg * 4 + 2) * 64 + lane) * 4] = acc2;
    *(f32x4*)&red[((pg * 4 + 3) * 64 + lane) * 4] = acc3;
  }
  __syncthreads();
  if (gsel == 0) {
    acc0 += *(const f32x4*)&red[((pg * 4 + 0) * 64 + lane) * 4];
    acc1 += *(const f32x4*)&red[((pg * 4 + 1) * 64 + lane) * 4];
    acc2 += *(const f32x4*)&red[((pg * 4 + 2) * 64 + lane) * 4];
    acc3 += *(const f32x4*)&red[((pg * 4 + 3) * 64 + lane) * 4];
    float* ob = out + pixin + kq * 4;
#pragma unroll
    for (int r = 0; r < 4; ++r) {
      ob[((b*64 +      colb) << 14) + r] = acc0[r];
      ob[((b*64 + 16 + colb) << 14) + r] = acc1[r];
      ob[((b*64 + 32 + colb) << 14) + r] = acc2[r];
      ob[((b*64 + 48 + colb) << 14) + r] = acc3[r];
    }
  }
}

extern "C" void kernel_launch(void* const* d_in, const int* in_sizes, int n_in,
                              void* d_out, int out_size, void* d_ws, size_t ws_size,
                              hipStream_t stream) {
  const float* x     = (const float*)d_in[0];
  const float* w_off = (const float*)d_in[1];
  const float* w_def = (const float*)d_in[2];
  float* out = (float*)d_out;

  char* ws = (char*)d_ws;
  ushort* xt     = (ushort*)ws;
  ushort* pk_def = (ushort*)(ws + XT_BYTES);
  ushort* pk_off = (ushort*)(ws + XT_BYTES + PKDEF_BYTES);

  transpose_cast<<<1024, 256, 0, stream>>>(x, xt);
  prep_pack<<<32, 256, 0, stream>>>(w_off, w_def, pk_def, pk_off);
  deform_fused<<<1024, 512, 0, stream>>>(xt, pk_def, pk_off, out);
}

// Round 10
// 49.942 us; speedup vs baseline: 1.6921x; 1.0752x over previous
//
#include <hip/hip_runtime.h>
#include <hip/hip_bf16.h>

typedef _Float16 f16x8 __attribute__((ext_vector_type(8)));
typedef _Float16 f16x2 __attribute__((ext_vector_type(2)));
typedef float f32x4  __attribute__((ext_vector_type(4)));

#define Bn 4
#define Cn 64
#define Hn 128
#define Wn 128
#define HWn 16384

// ws layout (bytes):
//   xt     [B][H][seg0..7][W][8ch] f16 @ 0   (8 MB)
//   pk_def [18][4][64][8] f16 @ XT_BYTES     B-frags, main conv
//   pk_off [18][3][64][8] f16 @ +PKDEF       B-frags, offset conv
#define XT_BYTES    (Bn*HWn*Cn*2)
#define PKDEF_BYTES (18*4*64*8*2)

static __device__ __forceinline__ unsigned pk_f16(float lo, float hi) {
  union { _Float16 h[2]; unsigned u; } cv;
  cv.h[0] = (_Float16)lo; cv.h[1] = (_Float16)hi;
  return cv.u;
}

// ---- x: NCHW f32 -> [b][y][seg][x][8] f16
__global__ __launch_bounds__(256) void transpose_cast(const float* __restrict__ x,
                                                      ushort* __restrict__ xt) {
  __shared__ float tile[64][65];
  const int t = threadIdx.x;
  const int blk = blockIdx.x;            // 1024 = B * 256
  const int b = blk >> 8;
  const int pix0 = (blk & 255) * 64;
  const int y = pix0 >> 7, x0 = pix0 & 127;
  const float* xb = x + (b * Cn) * HWn + pix0;
#pragma unroll
  for (int q = 0; q < 16; ++q) {
    int idx = q * 256 + t;
    int c = idx >> 6, p = idx & 63;
    tile[c][p] = xb[c * HWn + p];
  }
  __syncthreads();
  const int p = t & 63, cg = t >> 6;
#pragma unroll
  for (int half = 0; half < 2; ++half) {
    const int seg = cg * 2 + half;
    unsigned u[4];
#pragma unroll
    for (int j = 0; j < 4; ++j)
      u[j] = pk_f16(tile[seg * 8 + 2 * j][p], tile[seg * 8 + 2 * j + 1][p]);
    uint4 v = {u[0], u[1], u[2], u[3]};
    *(uint4*)(xt + (((((b << 7) + y) << 3) + seg) * 128 + x0 + p) * 8) = v;
  }
}

// ---- pack weights as MFMA B-fragments (f16)
__global__ __launch_bounds__(256) void prep_pack(const float* __restrict__ w_off,
                                                 const float* __restrict__ w_def,
                                                 ushort* __restrict__ pk_def,
                                                 ushort* __restrict__ pk_off) {
  const int t = blockIdx.x * 256 + threadIdx.x;
  if (t < 4608) {                        // 18*4*64
    int lane = t & 63, oc = (t >> 6) & 3, s = t >> 8;
    int g = s / 9, k = s % 9;
    int o = oc * 16 + (lane & 15);
    int cb = g * 32 + (lane >> 4) * 8;
    unsigned u[4];
#pragma unroll
    for (int j = 0; j < 4; ++j)
      u[j] = pk_f16(w_def[(o * Cn + cb + 2 * j) * 9 + k],
                    w_def[(o * Cn + cb + 2 * j + 1) * 9 + k]);
    uint4 v = {u[0], u[1], u[2], u[3]};
    *(uint4*)(pk_def + t * 8) = v;
  } else if (t < 8064) {                 // + 18*3*64
    int t2 = t - 4608;
    int lane = t2 & 63, r = t2 >> 6;     // r = s*3 + oc
    int oc = r % 3, s = r / 3;
    int k = s >> 1, chalf = s & 1;
    int o = oc * 16 + (lane & 15);
    int cb = chalf * 32 + (lane >> 4) * 8;
    unsigned u[4];
#pragma unroll
    for (int j = 0; j < 4; ++j) {
      float lo = (o < 36) ? w_off[(o * Cn + cb + 2 * j) * 9 + k] : 0.f;
      float hi = (o < 36) ? w_off[(o * Cn + cb + 2 * j + 1) * 9 + k] : 0.f;
      u[j] = pk_f16(lo, hi);
    }
    uint4 v = {u[0], u[1], u[2], u[3]};
    *(uint4*)(pk_off + (r * 64 + lane) * 8) = v;
  }
}

// ---- FUSED: 16x8 pixel tile, 1024 thr = 16 waves = 8 pixel-rows x 2 gsel.
// Grid 512 = exactly 2 blocks/CU resident -> no tail. LDS 62,592 B.
#define T_STRIDE (17*24*8)               // ushorts per channel-octet plane
__global__ __launch_bounds__(1024, 8) void deform_fused(const ushort* __restrict__ xt,
                                                        const ushort* __restrict__ pk_def,
                                                        const ushort* __restrict__ pk_off,
                                                        float* __restrict__ out) {
  __shared__ ushort tile[8 * 17 * 24 * 8];   // 52,224 B (reduce buf aliases later)
  __shared__ _Float16 off_lds[8][36][18];    // 10,368 B
  const int t = threadIdx.x;
  const int lane = t & 63;
  const int wid = t >> 6;                // 0..15
  const int pg = wid >> 1, gsel = wid & 1;
  int bid = blockIdx.x;
  bid = (bid & 7) * 64 + (bid >> 3);     // bijective XCD swizzle (512 % 8 == 0)
  const int b  = bid >> 7;
  const int ty = (bid >> 3) & 15;
  const int tx = bid & 7;
  const int y0t = ty * 8, x0t = tx * 16;
  const int TLY = max(0, y0t - 4), THY = min(127, y0t + 12);
  const int TLX = max(0, x0t - 3), THX = min(127, x0t + 19);
  const int Hd = THY - TLY + 1, Wd = THX - TLX + 1;

  { // stage [8 seg][Hd][Wd][8ch] -> LDS (coalesced 16B/lane)
    const int xq = t & 31;
    const int r0 = t >> 5;               // 32 row-groups
    const int nr = Hd * 8;
    for (int rr = r0; rr < nr; rr += 32) {
      const int yq = rr >> 3, seg = rr & 7;
      if (xq < Wd) {
        const ushort* src = xt + ((((b << 7) + TLY + yq) << 3) + seg) * 1024 + (TLX + xq) * 8;
        *(uint4*)&tile[seg * T_STRIDE + (yq * 24 + xq) * 8] = *(const uint4*)src;
      }
    }
  }
  __syncthreads();

  const int h = y0t + pg;
  const int p = lane & 15, kq = lane >> 4;
  const int w_ = x0t + p;
  const int pixin = (h << 7) + x0t;
  const int su = gsel * 4 + kq;
  const int colb = lane & 15;

  // hoisted per-tap data for the regular 3x3 (shared by ph1's two ch-halves)
  int pixoff[9]; bool tvalid[9];
#pragma unroll
  for (int kk = 0; kk < 9; ++kk) {
    int yk = h + kk / 3 - 1, xk = w_ + kk % 3 - 1;
    tvalid[kk] = ((unsigned)yk < 128u) && ((unsigned)xk < 128u);
    int yc = min(max(yk, 0), 127), xc = min(max(xk, 0), 127);
    pixoff[kk] = ((yc - TLY) * 24 + (xc - TLX)) * 8;
  }

  // ---- phase 1: offset conv from staged tile.
  // N-split: gsel0 -> off ch 0-15; gsel1 -> 16-31 & 32-35.
  {
    f32x4 oa0 = {0,0,0,0}, oa1 = {0,0,0,0}, oa2 = {0,0,0,0};
    const f16x8* pBo = (const f16x8*)pk_off;
#pragma unroll
    for (int s = 0; s < 18; ++s) {
      const int k = s >> 1, chalf = s & 1;
      uint4 t_ = *(const uint4*)&tile[(chalf * 4 + kq) * T_STRIDE + pixoff[k]];
      if (!tvalid[k]) { t_.x = 0; t_.y = 0; t_.z = 0; t_.w = 0; }
      union { uint4 u; f16x8 v; } A; A.u = t_;
      if (gsel == 0) {
        oa0 = __builtin_amdgcn_mfma_f32_16x16x32_f16(A.v, pBo[(s*3 + 0)*64 + lane], oa0, 0,0,0);
      } else {
        oa1 = __builtin_amdgcn_mfma_f32_16x16x32_f16(A.v, pBo[(s*3 + 1)*64 + lane], oa1, 0,0,0);
        oa2 = __builtin_amdgcn_mfma_f32_16x16x32_f16(A.v, pBo[(s*3 + 2)*64 + lane], oa2, 0,0,0);
      }
    }
    // D: col = lane&15 = offset channel (within 16-group), row = kq*4+r = pixel x
    if (gsel == 0) {
#pragma unroll
      for (int r = 0; r < 4; ++r) off_lds[pg][colb][kq * 4 + r] = (_Float16)oa0[r];
    } else {
#pragma unroll
      for (int r = 0; r < 4; ++r) {
        off_lds[pg][16 + colb][kq * 4 + r] = (_Float16)oa1[r];
        if (colb < 4) off_lds[pg][32 + colb][kq * 4 + r] = (_Float16)oa2[r];
      }
    }
  }
  __syncthreads();

  // this wave's 18 offset channels for its pixel (broadcast across kq)
  float offv[18];
#pragma unroll
  for (int j = 0; j < 18; ++j) offv[j] = (float)off_lds[pg][gsel * 18 + j][p];

  // ---- phase 2: deformable gather + packed-f16 bilinear + main MFMA
  f32x4 acc0={0,0,0,0}, acc1={0,0,0,0}, acc2={0,0,0,0}, acc3={0,0,0,0};
  const f16x8* pB = (const f16x8*)pk_def;

#pragma unroll
  for (int j = 0; j < 9; ++j) {
    const int k = j;
    float py = offv[2*j]   + (float)(h  + k / 3 - 1);
    float px = offv[2*j+1] + (float)(w_ + k % 3 - 1);
    float fy = floorf(py), fx = floorf(px);
    int y0 = (int)fy, x0 = (int)fx;
    float dy = py - fy, dx = px - fx;

    bool vy0 = (y0 >= 0) && (y0 < Hn);
    bool vy1 = (y0 >= -1) && (y0 < Hn - 1);
    bool vx0 = (x0 >= 0) && (x0 < Wn);
    bool vx1 = (x0 >= -1) && (x0 < Wn - 1);
    float omdy = 1.f - dy, omdx = 1.f - dx;
    float w00 = (vy0 && vx0) ? omdy * omdx : 0.f;
    float w01 = (vy0 && vx1) ? omdy * dx   : 0.f;
    float w10 = (vy1 && vx0) ? dy * omdx   : 0.f;
    float w11 = (vy1 && vx1) ? dy * dx     : 0.f;

    int iy0 = min(max(y0, 0), Hn - 1), iy1 = min(max(y0 + 1, 0), Hn - 1);
    int ix0 = min(max(x0, 0), Wn - 1), ix1 = min(max(x0 + 1, 0), Wn - 1);

    uint4 c00, c01, c10, c11;
    bool intile = (iy0 >= TLY) && (iy1 <= THY) && (ix0 >= TLX) && (ix1 <= THX);
    if (__all((int)intile)) {            // fast path: LDS
      const int base = su * T_STRIDE;
      const int ly0 = iy0 - TLY, ly1 = iy1 - TLY;
      const int lx0 = ix0 - TLX, lx1 = ix1 - TLX;
      c00 = *(const uint4*)&tile[base + (ly0 * 24 + lx0) * 8];
      c01 = *(const uint4*)&tile[base + (ly0 * 24 + lx1) * 8];
      c10 = *(const uint4*)&tile[base + (ly1 * 24 + lx0) * 8];
      c11 = *(const uint4*)&tile[base + (ly1 * 24 + lx1) * 8];
    } else {                             // rare fallback: global gather (L2-hot)
      const int r0g = ((((b << 7) + iy0) << 3) + su) * 128;
      const int r1g = ((((b << 7) + iy1) << 3) + su) * 128;
      c00 = *(const uint4*)(xt + (r0g + ix0) * 8);
      c01 = *(const uint4*)(xt + (r0g + ix1) * 8);
      c10 = *(const uint4*)(xt + (r1g + ix0) * 8);
      c11 = *(const uint4*)(xt + (r1g + ix1) * 8);
    }

    // packed-f16 bilinear: result words ARE the f16 MFMA A-fragment
    const _Float16 h00 = (_Float16)w00, h01 = (_Float16)w01;
    const _Float16 h10 = (_Float16)w10, h11 = (_Float16)w11;
    const f16x2 W00 = {h00, h00}, W01 = {h01, h01};
    const f16x2 W10 = {h10, h10}, W11 = {h11, h11};
    union U32H { unsigned u; f16x2 h; };
    union { uint4 u; f16x8 v; } A;
#define BILC(comp, fld)                                                        \
    { U32H a0, a1, a2, a3, r;                                                  \
      a0.u = c00.comp; a1.u = c01.comp; a2.u = c10.comp; a3.u = c11.comp;      \
      r.h = a0.h * W00 + a1.h * W01 + a2.h * W10 + a3.h * W11;                 \
      A.u.fld = r.u; }
    BILC(x, x) BILC(y, y) BILC(z, z) BILC(w, w)
#undef BILC

    const int s = gsel * 9 + j;
    acc0 = __builtin_amdgcn_mfma_f32_16x16x32_f16(A.v, pB[(s*4 + 0)*64 + lane], acc0, 0,0,0);
    acc1 = __builtin_amdgcn_mfma_f32_16x16x32_f16(A.v, pB[(s*4 + 1)*64 + lane], acc1, 0,0,0);
    acc2 = __builtin_amdgcn_mfma_f32_16x16x32_f16(A.v, pB[(s*4 + 2)*64 + lane], acc2, 0,0,0);
    acc3 = __builtin_amdgcn_mfma_f32_16x16x32_f16(A.v, pB[(s*4 + 3)*64 + lane], acc3, 0,0,0);
  }

  __syncthreads();                       // all waves done with tile
  float* red = (float*)tile;             // [8][4][64][4] f32 = 32 KB (aliases tile)
  if (gsel == 1) {
    *(f32x4*)&red[((pg * 4 + 0) * 64 + lane) * 4] = acc0;
    *(f32x4*)&red[((pg * 4 + 1) * 64 + lane) * 4] = acc1;
    *(f32x4*)&red[((pg * 4 + 2) * 64 + lane) * 4] = acc2;
    *(f32x4*)&red[((pg * 4 + 3) * 64 + lane) * 4] = acc3;
  }
  __syncthreads();
  if (gsel == 0) {
    acc0 += *(const f32x4*)&red[((pg * 4 + 0) * 64 + lane) * 4];
    acc1 += *(const f32x4*)&red[((pg * 4 + 1) * 64 + lane) * 4];
    acc2 += *(const f32x4*)&red[((pg * 4 + 2) * 64 + lane) * 4];
    acc3 += *(const f32x4*)&red[((pg * 4 + 3) * 64 + lane) * 4];
    float* ob = out + pixin + kq * 4;
#pragma unroll
    for (int r = 0; r < 4; ++r) {
      ob[((b*64 +      colb) << 14) + r] = acc0[r];
      ob[((b*64 + 16 + colb) << 14) + r] = acc1[r];
      ob[((b*64 + 32 + colb) << 14) + r] = acc2[r];
      ob[((b*64 + 48 + colb) << 14) + r] = acc3[r];
    }
  }
}

extern "C" void kernel_launch(void* const* d_in, const int* in_sizes, int n_in,
                              void* d_out, int out_size, void* d_ws, size_t ws_size,
                              hipStream_t stream) {
  const float* x     = (const float*)d_in[0];
  const float* w_off = (const float*)d_in[1];
  const float* w_def = (const float*)d_in[2];
  float* out = (float*)d_out;

  char* ws = (char*)d_ws;
  ushort* xt     = (ushort*)ws;
  ushort* pk_def = (ushort*)(ws + XT_BYTES);
  ushort* pk_off = (ushort*)(ws + XT_BYTES + PKDEF_BYTES);

  transpose_cast<<<1024, 256, 0, stream>>>(x, xt);
  prep_pack<<<32, 256, 0, stream>>>(w_off, w_def, pk_def, pk_off);
  deform_fused<<<512, 1024, 0, stream>>>(xt, pk_def, pk_off, out);
}